// Round 1
// baseline (256.159 us; speedup 1.0000x reference)
//
#include <hip/hip_runtime.h>

// Problem constants (from reference setup_inputs)
#define BB 4
#define CC 12
#define DD 8
#define HG 16
#define WG 16
#define HH 1024
#define WW 1024

// ---------------------------------------------------------------------------
// Kernel 1: transpose grid [B,C,D,Hg,Wg] -> [B,D,Hg,Wg,C] so the 12 channels
// of one grid cell are contiguous (3x float4 per trilinear corner).
// Total: 98304 elements, trivial cost.
// ---------------------------------------------------------------------------
__global__ void transpose_grid(const float* __restrict__ g, float* __restrict__ gt) {
    int o = blockIdx.x * blockDim.x + threadIdx.x;
    if (o >= BB * DD * HG * WG * CC) return;
    int c = o % CC; int t = o / CC;
    int x = t % WG; t /= WG;
    int y = t % HG; t /= HG;
    int d = t % DD; int b = t / DD;
    gt[o] = g[(((b * CC + c) * DD + d) * HG + y) * WG + x];
}

// ---------------------------------------------------------------------------
// Kernel 2: per-pixel trilinear slice of the (transposed) grid + affine apply.
// One block per (b,h) row; 256 threads x 4 pixels (float4 I/O).
// TRANSPOSED=false fallback reads the original layout with scalar loads
// (only used if ws_size is unexpectedly too small).
// ---------------------------------------------------------------------------
template <bool TRANSPOSED>
__global__ __launch_bounds__(256) void slice_apply(
    const float* __restrict__ gsrc,   // TRANSPOSED ? [B,D,HG,WG,C] : [B,C,D,HG,WG]
    const float* __restrict__ guide,  // [B,H,W]
    const float* __restrict__ img,    // [B,3,H,W]
    float* __restrict__ out)          // [B,3,H,W]
{
    const int bh = blockIdx.x;
    const int b = bh >> 10;          // H = 1024
    const int h = bh & (HH - 1);
    const int w0 = threadIdx.x * 4;

    // y interpolation (uniform across the row)
    const float gy  = (h + 0.5f) * ((float)HG / (float)HH);
    const float fy  = floorf(gy - 0.5f);
    const float ty  = gy - 0.5f - fy;
    const int   iy0 = max(0, min(HG - 1, (int)fy));
    const int   iy1 = max(0, min(HG - 1, (int)fy + 1));
    const float wy0 = 1.0f - ty, wy1 = ty;

    const size_t pix = ((size_t)b * HH + h) * WW + w0;
    const float4 g4 = *reinterpret_cast<const float4*>(guide + pix);
    const float* ib = img + (((size_t)b * 3) * HH + h) * WW + w0;
    const float4 i0 = *reinterpret_cast<const float4*>(ib);
    const float4 i1 = *reinterpret_cast<const float4*>(ib + (size_t)HH * WW);
    const float4 i2 = *reinterpret_cast<const float4*>(ib + (size_t)2 * HH * WW);

    float4 o0, o1, o2;

    #pragma unroll
    for (int p = 0; p < 4; ++p) {
        const int w = w0 + p;
        // x interpolation
        const float gx  = (w + 0.5f) * ((float)WG / (float)WW);
        const float fx  = floorf(gx - 0.5f);
        const float tx  = gx - 0.5f - fx;
        const int   ix0 = max(0, min(WG - 1, (int)fx));
        const int   ix1 = max(0, min(WG - 1, (int)fx + 1));
        const float wx0 = 1.0f - tx, wx1 = tx;
        // z interpolation (guide-driven)
        const float gv = (p == 0) ? g4.x : (p == 1) ? g4.y : (p == 2) ? g4.z : g4.w;
        const float gz  = gv * (float)DD;
        const float fz  = floorf(gz - 0.5f);
        const float tz  = gz - 0.5f - fz;
        const int   iz0 = max(0, min(DD - 1, (int)fz));
        const int   iz1 = max(0, min(DD - 1, (int)fz + 1));
        const float wz0 = 1.0f - tz, wz1 = tz;

        const int   zs[2] = {iz0, iz1}; const float wzs[2] = {wz0, wz1};
        const int   ys[2] = {iy0, iy1}; const float wys[2] = {wy0, wy1};
        const int   xs[2] = {ix0, ix1}; const float wxs[2] = {wx0, wx1};

        float c[12];
        #pragma unroll
        for (int k = 0; k < 12; ++k) c[k] = 0.0f;

        #pragma unroll
        for (int iz = 0; iz < 2; ++iz) {
            #pragma unroll
            for (int iy = 0; iy < 2; ++iy) {
                #pragma unroll
                for (int ix = 0; ix < 2; ++ix) {
                    const float wgt = wzs[iz] * wys[iy] * wxs[ix];
                    if (TRANSPOSED) {
                        const float* p4 = gsrc + (size_t)b * (DD * HG * WG * CC)
                                        + ((size_t)(zs[iz] * HG + ys[iy]) * WG + xs[ix]) * CC;
                        const float4 a = *reinterpret_cast<const float4*>(p4);
                        const float4 bq = *reinterpret_cast<const float4*>(p4 + 4);
                        const float4 cq = *reinterpret_cast<const float4*>(p4 + 8);
                        c[0] += wgt * a.x;  c[1] += wgt * a.y;  c[2]  += wgt * a.z;  c[3]  += wgt * a.w;
                        c[4] += wgt * bq.x; c[5] += wgt * bq.y; c[6]  += wgt * bq.z; c[7]  += wgt * bq.w;
                        c[8] += wgt * cq.x; c[9] += wgt * cq.y; c[10] += wgt * cq.z; c[11] += wgt * cq.w;
                    } else {
                        const size_t base = (size_t)b * (CC * DD * HG * WG)
                                          + (size_t)(zs[iz] * HG + ys[iy]) * WG + xs[ix];
                        #pragma unroll
                        for (int ch = 0; ch < 12; ++ch)
                            c[ch] += wgt * gsrc[base + (size_t)ch * (DD * HG * WG)];
                    }
                }
            }
        }

        const float im0 = (p == 0) ? i0.x : (p == 1) ? i0.y : (p == 2) ? i0.z : i0.w;
        const float im1 = (p == 0) ? i1.x : (p == 1) ? i1.y : (p == 2) ? i1.z : i1.w;
        const float im2 = (p == 0) ? i2.x : (p == 1) ? i2.y : (p == 2) ? i2.z : i2.w;

        const float r0 = c[0] * im0 + c[1] * im1 + c[2]  * im2 + c[3];
        const float r1 = c[4] * im0 + c[5] * im1 + c[6]  * im2 + c[7];
        const float r2 = c[8] * im0 + c[9] * im1 + c[10] * im2 + c[11];

        if (p == 0) { o0.x = r0; o1.x = r1; o2.x = r2; }
        if (p == 1) { o0.y = r0; o1.y = r1; o2.y = r2; }
        if (p == 2) { o0.z = r0; o1.z = r1; o2.z = r2; }
        if (p == 3) { o0.w = r0; o1.w = r1; o2.w = r2; }
    }

    float* ob = out + (((size_t)b * 3) * HH + h) * WW + w0;
    *reinterpret_cast<float4*>(ob) = o0;
    *reinterpret_cast<float4*>(ob + (size_t)HH * WW) = o1;
    *reinterpret_cast<float4*>(ob + (size_t)2 * HH * WW) = o2;
}

extern "C" void kernel_launch(void* const* d_in, const int* in_sizes, int n_in,
                              void* d_out, int out_size, void* d_ws, size_t ws_size,
                              hipStream_t stream) {
    const float* grid  = (const float*)d_in[0];
    const float* guide = (const float*)d_in[1];
    const float* image = (const float*)d_in[2];
    float* out = (float*)d_out;

    const size_t need = (size_t)BB * DD * HG * WG * CC * sizeof(float);
    const int nrows = BB * HH;  // 4096 blocks, one per (b,h) row

    if (ws_size >= need) {
        float* gt = (float*)d_ws;
        const int n = BB * DD * HG * WG * CC;
        transpose_grid<<<(n + 255) / 256, 256, 0, stream>>>(grid, gt);
        slice_apply<true><<<nrows, 256, 0, stream>>>(gt, guide, image, out);
    } else {
        slice_apply<false><<<nrows, 256, 0, stream>>>(grid, guide, image, out);
    }
}

// Round 2
// 124.593 us; speedup vs baseline: 2.0560x; 2.0560x over previous
//
#include <hip/hip_runtime.h>

// Problem constants (from reference setup_inputs)
#define BB 4
#define CC 12
#define DD 8
#define HG 16
#define WG 16
#define HH 1024
#define WW 1024

// LDS slab layout: S[x*XSTRIDE + z*CC + c], y-interpolation pre-folded.
// XSTRIDE = 8*12 + 8 pad floats = 104 -> cells stay 16B-aligned and
// bank = (8x + 12z + c) % 32 spreads the guide-random z across banks.
#define XSTRIDE 104

__global__ __launch_bounds__(256) void slice_apply(
    const float* __restrict__ grid,   // [B,C,D,HG,WG]
    const float* __restrict__ guide,  // [B,H,W]
    const float* __restrict__ img,    // [B,3,H,W]
    float* __restrict__ out)          // [B,3,H,W]
{
    __shared__ float S[WG * XSTRIDE];  // 6656 B

    const int bh = blockIdx.x;
    const int b = bh >> 10;          // H = 1024
    const int h = bh & (HH - 1);

    // y interpolation (uniform across the row) — folded into the LDS slab
    const float gy  = (h + 0.5f) * ((float)HG / (float)HH);
    const float fy  = floorf(gy - 0.5f);
    const float ty  = gy - 0.5f - fy;
    const int   iy0 = max(0, min(HG - 1, (int)fy));
    const int   iy1 = max(0, min(HG - 1, (int)fy + 1));
    const float wy0 = 1.0f - ty, wy1 = ty;

    // Stage: S[x][z][c] = wy0*G[b,c,z,iy0,x] + wy1*G[b,c,z,iy1,x]
    // Flat index ordered (c,z,x) so consecutive threads read consecutive x.
    for (int j = threadIdx.x; j < CC * DD * WG; j += 256) {
        const int x = j & 15;
        const int z = (j >> 4) & 7;
        const int c = j >> 7;
        const size_t base = ((size_t)(b * CC + c) * DD + z) * (HG * WG);
        const float v0 = grid[base + iy0 * WG + x];
        const float v1 = grid[base + iy1 * WG + x];
        S[x * XSTRIDE + z * CC + c] = wy0 * v0 + wy1 * v1;
    }
    __syncthreads();

    const int w0 = threadIdx.x * 4;

    // x cell pair is uniform across the 4 pixels of this thread
    // (fx changes only at w ≡ 31.5 mod 64 — never inside a 4-aligned group)
    const float scale = (float)WG / (float)WW;       // 1/64
    const float gx0 = (w0 + 0.5f) * scale;
    const float fx  = floorf(gx0 - 0.5f);
    const float tx0 = gx0 - 0.5f - fx;
    const int   ix0 = max(0, min(WG - 1, (int)fx));
    const int   ix1 = max(0, min(WG - 1, (int)fx + 1));
    const float* Sx0 = S + ix0 * XSTRIDE;
    const float* Sx1 = S + ix1 * XSTRIDE;

    const size_t pix = ((size_t)b * HH + h) * WW + w0;
    const float4 g4 = *reinterpret_cast<const float4*>(guide + pix);
    const float* ib = img + (((size_t)b * 3) * HH + h) * WW + w0;
    const float4 i0 = *reinterpret_cast<const float4*>(ib);
    const float4 i1 = *reinterpret_cast<const float4*>(ib + (size_t)HH * WW);
    const float4 i2 = *reinterpret_cast<const float4*>(ib + (size_t)2 * HH * WW);

    float4 o0, o1, o2;

    #pragma unroll
    for (int p = 0; p < 4; ++p) {
        const float tx  = tx0 + (float)p * scale;
        const float wx0 = 1.0f - tx, wx1 = tx;

        const float gv = (p == 0) ? g4.x : (p == 1) ? g4.y : (p == 2) ? g4.z : g4.w;
        const float gz  = gv * (float)DD;
        const float fz  = floorf(gz - 0.5f);
        const float tz  = gz - 0.5f - fz;
        const int   iz0 = max(0, min(DD - 1, (int)fz));
        const int   iz1 = max(0, min(DD - 1, (int)fz + 1));
        const float wz0 = 1.0f - tz, wz1 = tz;

        const float w00 = wz0 * wx0, w01 = wz0 * wx1;
        const float w10 = wz1 * wx0, w11 = wz1 * wx1;

        float acc[12];
        #pragma unroll
        for (int k = 0; k < 12; ++k) acc[k] = 0.0f;

        auto accum = [&](const float* P, float w) {
            const float4 a = *reinterpret_cast<const float4*>(P);
            const float4 e = *reinterpret_cast<const float4*>(P + 4);
            const float4 f = *reinterpret_cast<const float4*>(P + 8);
            acc[0] += w * a.x;  acc[1] += w * a.y;  acc[2]  += w * a.z;  acc[3]  += w * a.w;
            acc[4] += w * e.x;  acc[5] += w * e.y;  acc[6]  += w * e.z;  acc[7]  += w * e.w;
            acc[8] += w * f.x;  acc[9] += w * f.y;  acc[10] += w * f.z;  acc[11] += w * f.w;
        };
        accum(Sx0 + iz0 * CC, w00);
        accum(Sx1 + iz0 * CC, w01);
        accum(Sx0 + iz1 * CC, w10);
        accum(Sx1 + iz1 * CC, w11);

        const float im0 = (p == 0) ? i0.x : (p == 1) ? i0.y : (p == 2) ? i0.z : i0.w;
        const float im1 = (p == 0) ? i1.x : (p == 1) ? i1.y : (p == 2) ? i1.z : i1.w;
        const float im2 = (p == 0) ? i2.x : (p == 1) ? i2.y : (p == 2) ? i2.z : i2.w;

        const float r0 = acc[0] * im0 + acc[1] * im1 + acc[2]  * im2 + acc[3];
        const float r1 = acc[4] * im0 + acc[5] * im1 + acc[6]  * im2 + acc[7];
        const float r2 = acc[8] * im0 + acc[9] * im1 + acc[10] * im2 + acc[11];

        if (p == 0) { o0.x = r0; o1.x = r1; o2.x = r2; }
        if (p == 1) { o0.y = r0; o1.y = r1; o2.y = r2; }
        if (p == 2) { o0.z = r0; o1.z = r1; o2.z = r2; }
        if (p == 3) { o0.w = r0; o1.w = r1; o2.w = r2; }
    }

    float* ob = out + (((size_t)b * 3) * HH + h) * WW + w0;
    *reinterpret_cast<float4*>(ob) = o0;
    *reinterpret_cast<float4*>(ob + (size_t)HH * WW) = o1;
    *reinterpret_cast<float4*>(ob + (size_t)2 * HH * WW) = o2;
}

extern "C" void kernel_launch(void* const* d_in, const int* in_sizes, int n_in,
                              void* d_out, int out_size, void* d_ws, size_t ws_size,
                              hipStream_t stream) {
    const float* grid  = (const float*)d_in[0];
    const float* guide = (const float*)d_in[1];
    const float* image = (const float*)d_in[2];
    float* out = (float*)d_out;

    const int nrows = BB * HH;  // 4096 blocks, one per (b,h) row
    slice_apply<<<nrows, 256, 0, stream>>>(grid, guide, image, out);
}

// Round 4
// 121.470 us; speedup vs baseline: 2.1088x; 1.0257x over previous
//
#include <hip/hip_runtime.h>

// Problem constants (from reference setup_inputs)
#define BB 4
#define CC 12
#define DD 8
#define HG 16
#define WG 16
#define HH 1024
#define WW 1024

// Native 4-float vector (clang ext vector) — legal operand for
// __builtin_nontemporal_load/store, unlike HIP_vector_type<float,4>.
typedef float vf4 __attribute__((ext_vector_type(4)));

// LDS slab layout per row: S[x*XSTRIDE + z*CC + c], y-interpolation pre-folded.
// XSTRIDE = 8*12 + 8 pad floats = 104 -> cells stay 16B-aligned and
// bank = (8x + 12z + c) % 32 spreads the guide-random z across banks.
#define XSTRIDE 104
#define ROWS 4   // rows per block; 4-aligned groups never straddle an fy band
                 // (fy increments at h = 32 + 64k, which is 0 mod 4)

__global__ __launch_bounds__(256) void slice_apply(
    const float* __restrict__ grid,   // [B,C,D,HG,WG]
    const float* __restrict__ guide,  // [B,H,W]
    const float* __restrict__ img,    // [B,3,H,W]
    float* __restrict__ out)          // [B,3,H,W]
{
    __shared__ float S[ROWS * WG * XSTRIDE];  // 4 * 6656 B = 26624 B

    const int blk = blockIdx.x;
    const int b  = blk >> 8;                 // HH/ROWS = 256 row-groups per batch
    const int h0 = (blk & 255) * ROWS;

    // y-cell pair shared by all ROWS rows of this block
    const float gy0 = (h0 + 0.5f) * ((float)HG / (float)HH);
    const float fy  = floorf(gy0 - 0.5f);
    const int   iy0 = max(0, min(HG - 1, (int)fy));
    const int   iy1 = max(0, min(HG - 1, (int)fy + 1));

    float wy1r[ROWS];
    #pragma unroll
    for (int r = 0; r < ROWS; ++r) {
        const float gy = (h0 + r + 0.5f) * ((float)HG / (float)HH);
        wy1r[r] = gy - 0.5f - fy;           // ty in [0,1)
    }

    // Stage: load the two raw y-slices once, fold into ROWS per-row slabs.
    // 1536 cells; flat index ordered (c,z,x) so consecutive threads read
    // consecutive x (coalesced 64B segments).
    for (int j = threadIdx.x; j < CC * DD * WG; j += 256) {
        const int x = j & 15;
        const int z = (j >> 4) & 7;
        const int c = j >> 7;
        const size_t base = ((size_t)(b * CC + c) * DD + z) * (HG * WG);
        const float v0 = grid[base + iy0 * WG + x];
        const float v1 = grid[base + iy1 * WG + x];
        const int so = x * XSTRIDE + z * CC + c;
        #pragma unroll
        for (int r = 0; r < ROWS; ++r) {
            const float ty = wy1r[r];
            S[r * (WG * XSTRIDE) + so] = v0 + ty * (v1 - v0);
        }
    }
    __syncthreads();

    const int w0 = threadIdx.x * 4;

    // x cell pair is uniform across the 4 pixels of this thread
    const float scale = (float)WG / (float)WW;       // 1/64
    const float gx0 = (w0 + 0.5f) * scale;
    const float fx  = floorf(gx0 - 0.5f);
    const float tx0 = gx0 - 0.5f - fx;
    const int   ix0 = max(0, min(WG - 1, (int)fx));
    const int   ix1 = max(0, min(WG - 1, (int)fx + 1));

    #pragma unroll
    for (int r = 0; r < ROWS; ++r) {
        const int h = h0 + r;
        const float* Sr  = S + r * (WG * XSTRIDE);
        const float* Sx0 = Sr + ix0 * XSTRIDE;
        const float* Sx1 = Sr + ix1 * XSTRIDE;

        const size_t pix = ((size_t)b * HH + h) * WW + w0;
        const vf4 g4 = *reinterpret_cast<const vf4*>(guide + pix);
        const float* ib = img + (((size_t)b * 3) * HH + h) * WW + w0;
        const vf4 i0 = __builtin_nontemporal_load(reinterpret_cast<const vf4*>(ib));
        const vf4 i1 = __builtin_nontemporal_load(reinterpret_cast<const vf4*>(ib + (size_t)HH * WW));
        const vf4 i2 = __builtin_nontemporal_load(reinterpret_cast<const vf4*>(ib + (size_t)2 * HH * WW));

        vf4 o0, o1, o2;

        #pragma unroll
        for (int p = 0; p < 4; ++p) {
            const float tx  = tx0 + (float)p * scale;
            const float wx0 = 1.0f - tx, wx1 = tx;

            const float gv = g4[p];
            const float gz  = gv * (float)DD;
            const float fz  = floorf(gz - 0.5f);
            const float tz  = gz - 0.5f - fz;
            const int   iz0 = max(0, min(DD - 1, (int)fz));
            const int   iz1 = max(0, min(DD - 1, (int)fz + 1));
            const float wz0 = 1.0f - tz, wz1 = tz;

            const float w00 = wz0 * wx0, w01 = wz0 * wx1;
            const float w10 = wz1 * wx0, w11 = wz1 * wx1;

            float acc[12];
            #pragma unroll
            for (int k = 0; k < 12; ++k) acc[k] = 0.0f;

            auto accum = [&](const float* P, float w) {
                const vf4 a = *reinterpret_cast<const vf4*>(P);
                const vf4 e = *reinterpret_cast<const vf4*>(P + 4);
                const vf4 f = *reinterpret_cast<const vf4*>(P + 8);
                #pragma unroll
                for (int k = 0; k < 4; ++k) {
                    acc[k]     += w * a[k];
                    acc[4 + k] += w * e[k];
                    acc[8 + k] += w * f[k];
                }
            };
            accum(Sx0 + iz0 * CC, w00);
            accum(Sx1 + iz0 * CC, w01);
            accum(Sx0 + iz1 * CC, w10);
            accum(Sx1 + iz1 * CC, w11);

            const float im0 = i0[p];
            const float im1 = i1[p];
            const float im2 = i2[p];

            o0[p] = acc[0] * im0 + acc[1] * im1 + acc[2]  * im2 + acc[3];
            o1[p] = acc[4] * im0 + acc[5] * im1 + acc[6]  * im2 + acc[7];
            o2[p] = acc[8] * im0 + acc[9] * im1 + acc[10] * im2 + acc[11];
        }

        float* ob = out + (((size_t)b * 3) * HH + h) * WW + w0;
        __builtin_nontemporal_store(o0, reinterpret_cast<vf4*>(ob));
        __builtin_nontemporal_store(o1, reinterpret_cast<vf4*>(ob + (size_t)HH * WW));
        __builtin_nontemporal_store(o2, reinterpret_cast<vf4*>(ob + (size_t)2 * HH * WW));
    }
}

extern "C" void kernel_launch(void* const* d_in, const int* in_sizes, int n_in,
                              void* d_out, int out_size, void* d_ws, size_t ws_size,
                              hipStream_t stream) {
    const float* grid  = (const float*)d_in[0];
    const float* guide = (const float*)d_in[1];
    const float* image = (const float*)d_in[2];
    float* out = (float*)d_out;

    const int nblocks = BB * HH / ROWS;  // 1024 blocks, 4 rows each
    slice_apply<<<nblocks, 256, 0, stream>>>(grid, guide, image, out);
}